// Round 7
// baseline (19.851 us; speedup 1.0000x reference)
//
#include <hip/hip_runtime.h>
#include <math.h>

#define BN_EPS 1e-5f
#define LWIN   193     // 256 - 64 + 1 windows
#define WPB    16      // windows per block
#define NBL    13      // ceil(193/16)
#define SLOC   96      // local sequence positions per block (79 real + halo)
#define STR    97      // LDS row stride for phase arrays

typedef __attribute__((address_space(1))) const unsigned int gl_u32;
typedef __attribute__((address_space(3))) unsigned int lds_u32;

__device__ __forceinline__ float elu(float x) { return x > 0.f ? x : expm1f(x); }

// Single kernel (r6's 2-kernel split regressed: serialization > saved FLOPs).
// Grid (16 batch, 13 window-chunks) x 512 threads (8 waves).
// Block (b, wb): windows l in [L0, L0+16), local i -> global s = g0 + i.
// Phases: stage | U | E | Q+Y1 | Ef | Y2  (4 barriers after staging).
// P2 is recomputed inline (bit-identical clamps to r5); S5 summed on the fly
// in Y2 (all positions real). Clamp-junk only feeds discarded terms (r3/r5
// validated this slice algebra at absmax 0.0).
__global__ __launch_bounds__(512) void eegnet_fused(
    const float* __restrict__ eeg,
    const float* __restrict__ c1w, const float* __restrict__ c1b,
    const float* __restrict__ bn1g, const float* __restrict__ bn1b,
    const float* __restrict__ bn1m, const float* __restrict__ bn1v,
    const float* __restrict__ w2,  const float* __restrict__ c2b,
    const float* __restrict__ bn2g, const float* __restrict__ bn2b,
    const float* __restrict__ bn2m, const float* __restrict__ bn2v,
    const float* __restrict__ c3w, const float* __restrict__ c3b,
    const float* __restrict__ c4w, const float* __restrict__ c4b,
    const float* __restrict__ bn3g, const float* __restrict__ bn3b,
    const float* __restrict__ bn3m, const float* __restrict__ bn3v,
    const float* __restrict__ linw, const float* __restrict__ linb,
    float* __restrict__ out)
{
    const int b   = blockIdx.x;
    const int L0  = blockIdx.y * WPB;
    const int g0  = L0 - 3;
    const int tid = threadIdx.x;
    const int lane16 = tid & 15;
    const int grp32  = tid >> 4;     // 0..31

    __shared__ __align__(16) float Eg[64 * SLOC];   // eeg slice, stride 96
    __shared__ float2 w2t2[64 * 8];  // [c][o8]: channels 2*o8, 2*o8+1
    __shared__ float  Ul[16][STR], El[16][STR], Ql[16][STR], Ef[16][STR];
    __shared__ float  cs[512];
    __shared__ float  q0s[16][17], q1s[16][17];

    const float* ebase = eeg + b * 64 * 256;

    // ---- stage eeg -> LDS: 24 DMA chunk-instrs (3/wave); per-element clamped
    //      fallback for edge chunks (r4's per-chunk clamp shifted data) ----
    {
        const int wv = tid >> 6, ln = tid & 63;
        #pragma unroll
        for (int j = 0; j < 3; ++j) {
            const int n    = wv * 3 + j;          // 0..23
            const int fidx = n * 256 + ln * 4;    // dest float index
            const int c    = fidx / SLOC;         // SLOC%4==0 -> chunk in-row
            const int i    = fidx - c * SLOC;
            const int s    = g0 + i;
            if (s >= 0 && s <= 252) {
                __builtin_amdgcn_global_load_lds((gl_u32*)(ebase + c * 256 + s),
                                                 (lds_u32*)&Eg[n * 256], 16, 0, 0);
            } else {
                const float* row = ebase + c * 256;
                const int e0 = s     < 0 ? 0 : (s     > 255 ? 255 : s);
                const int e1 = s + 1 < 0 ? 0 : (s + 1 > 255 ? 255 : s + 1);
                const int e2 = s + 2 < 0 ? 0 : (s + 2 > 255 ? 255 : s + 2);
                const int e3 = s + 3 < 0 ? 0 : (s + 3 > 255 ? 255 : s + 3);
                *reinterpret_cast<float4*>(&Eg[fidx]) =
                    make_float4(row[e0], row[e1], row[e2], row[e3]);
            }
        }
    }

    // ---- w2 -> LDS as per-wave channel pairs ----
    {
        const int o8 = tid >> 6, c = tid & 63;
        w2t2[c * 8 + o8] = make_float2(w2[(2 * o8    ) * 64 + c],
                                       w2[(2 * o8 + 1) * 64 + c]);
    }

    // ---- fold constants (layout as r5) ----
    if (tid < 64) {
        const int f = tid & 15, q = tid >> 4;
        float s2p = 0.f;
        #pragma unroll
        for (int k = 0; k < 16; ++k) s2p += w2[f * 64 + q * 16 + k];
        s2p += __shfl_xor(s2p, 16);
        s2p += __shfl_xor(s2p, 32);
        if (tid < 16) {
            const int g = f >> 1;
            const float s1 = bn1g[g] / sqrtf(bn1v[g] + BN_EPS);
            const float o1 = bn1b[g] - bn1m[g] * s1;
            const float s2 = bn2g[f] / sqrtf(bn2v[f] + BN_EPS);
            const float o2 = bn2b[f] - bn2m[f] * s2;
            const float ss = s2 * s1;
            cs[      f] = ss * c1w[g * 3 + 0];
            cs[ 16 + f] = ss * c1w[g * 3 + 1];
            cs[ 32 + f] = ss * c1w[g * 3 + 2];
            cs[ 48 + f] = s2 * (fmaf(s1, c1b[g], o1) * s2p + c2b[f]) + o2;
            cs[ 64 + f] = c3w[f * 3 + 0];
            cs[ 80 + f] = c3w[f * 3 + 1];
            cs[ 96 + f] = c3w[f * 3 + 2];
            cs[112 + f] = c3b[f];
        }
    } else if (tid < 128) {
        const int j = tid - 64, f = j & 15, quad = j >> 4;
        const float s3 = bn3g[f] / sqrtf(bn3v[f] + BN_EPS);
        if (quad == 0)
            cs[128 + f] = fmaf(s3, c4b[f], bn3b[f] - bn3m[f] * s3);
        #pragma unroll
        for (int k = 0; k < 4; ++k) {
            const int o = quad * 4 + k;
            cs[144 + o * 16 + f] = s3 * c4w[f * 16 + o];
        }
    } else if (tid < 224) {
        cs[400 + tid - 128] = linw[tid - 128];
    } else if (tid == 224) {
        cs[496] = linb[0];
    }
    __syncthreads();   // drains DMA + ds_writes + fold

    // ---- U phase: wave o8 owns channels 2*o8, 2*o8+1 ----
    {
        const int p = tid & 63, o8 = tid >> 6;
        const bool two = (p < 32);       // lanes 0..31 also do position p+64
        float a0 = 0.f, a1 = 0.f, b0 = 0.f, b1 = 0.f;
        #pragma unroll 8
        for (int c = 0; c < 64; ++c) {
            const float2 w = w2t2[c * 8 + o8];       // wave-uniform broadcast
            const float  e = Eg[c * SLOC + p];       // 2-way max (free)
            a0 = fmaf(w.x, e, a0); a1 = fmaf(w.y, e, a1);
            if (two) {
                const float e2 = Eg[c * SLOC + p + 64];
                b0 = fmaf(w.x, e2, b0); b1 = fmaf(w.y, e2, b1);
            }
        }
        const int o0 = 2 * o8;
        Ul[o0][p] = a0; Ul[o0 + 1][p] = a1;
        if (two) { Ul[o0][p + 64] = b0; Ul[o0 + 1][p + 64] = b1; }
    }
    __syncthreads();

    // ---- E phase (global zero-pad at s=0 / s=255) ----
    #pragma unroll
    for (int k = 0; k < 3; ++k) {
        const int i = grp32 + 32 * k, sg = g0 + i, o = lane16;
        const float um = (sg >= 1)   ? Ul[o][i > 0 ? i - 1 : 0] : 0.f;
        const float uc = Ul[o][i];
        const float up = (sg <= 254) ? Ul[o][i < SLOC - 1 ? i + 1 : SLOC - 1] : 0.f;
        El[o][i] = elu(fmaf(cs[o], um, fmaf(cs[16 + o], uc, fmaf(cs[32 + o], up, cs[48 + o]))));
    }
    __syncthreads();

    // ---- Q phase (P2 inline, bit-identical clamps) + Y1 fused ----
    {
        const int o = lane16;
        #pragma unroll
        for (int k = 0; k < 3; ++k) {
            const int i  = grp32 + 32 * k;
            const int im = i >= 2 ? i - 2 : 0;
            const int ip = i < SLOC - 2 ? i + 2 : SLOC - 1;
            const float pm = 0.5f * (El[o][im] + El[o][im < SLOC - 1 ? im + 1 : SLOC - 1]);
            const float pc = 0.5f * (El[o][i ] + El[o][i  < SLOC - 1 ? i  + 1 : SLOC - 1]);
            const float pp = 0.5f * (El[o][ip] + El[o][ip < SLOC - 1 ? ip + 1 : SLOC - 1]);
            Ql[o][i] = fmaf(cs[64 + o], pm,
                       fmaf(cs[80 + o], pc,
                       fmaf(cs[96 + o], pp, cs[112 + o])));
        }
        // Y1: thread (w, o, half) -> q0s or q1s
        const int w = grp32 & 15, half = grp32 >> 4, l = L0 + w;
        if (l < LWIN) {
            const int li = w + 3;
            const float z0 = fmaf(cs[16 + o], Ul[o][li],
                             fmaf(cs[32 + o], Ul[o][li + 1], cs[48 + o]));
            const float P0 = 0.5f * (elu(z0) + El[o][li + 1]);
            const float pa = 0.5f * (El[o][li + 2] + El[o][li + 3]);
            if (half == 0) {
                q0s[w][o] = fmaf(cs[80 + o], P0, fmaf(cs[96 + o], pa, cs[112 + o]));
            } else {
                const float pb = 0.5f * (El[o][li + 4] + El[o][li + 5]);
                q1s[w][o] = fmaf(cs[64 + o], P0,
                            fmaf(cs[80 + o], pa, fmaf(cs[96 + o], pb, cs[112 + o])));
            }
        }
    }
    __syncthreads();

    // ---- Ef phase: 1x1 conv + bn3 + elu ----
    #pragma unroll
    for (int k = 0; k < 3; ++k) {
        const int i = grp32 + 32 * k, f = lane16;
        float r = cs[128 + f];
        #pragma unroll
        for (int o = 0; o < 16; ++o)
            r = fmaf(cs[144 + o * 16 + f], Ql[o][i], r);
        Ef[f][i] = elu(r);
    }
    __syncthreads();

    // ---- Y2: thread (w, f, h); h=0 -> r0 + pool groups 0-2, h=1 -> r1 + 3-5 ----
    {
        const int w = tid >> 5, lane32 = tid & 31;
        const int f = lane32 & 15, h = lane32 >> 4;
        const int l = L0 + w;
        float part = 0.f;
        if (l < LWIN) {
            const int li = w + 3;
            float r = cs[128 + f];
            const float* q = h ? &q1s[w][0] : &q0s[w][0];
            #pragma unroll
            for (int o = 0; o < 16; ++o)
                r = fmaf(cs[144 + o * 16 + f], q[o], r);
            part = cs[400 + f * 6] * (elu(r) - Ef[f][li + 2 * h]);
            #pragma unroll
            for (int gg = 0; gg < 3; ++gg) {
                const int g = h * 3 + gg;
                const int p0 = li + 10 * g;
                const float s5 = Ef[f][p0] + Ef[f][p0 + 2] + Ef[f][p0 + 4]
                               + Ef[f][p0 + 6] + Ef[f][p0 + 8];
                part = fmaf(cs[400 + f * 6 + g], s5, part);
            }
        }
        part += __shfl_xor(part, 1);
        part += __shfl_xor(part, 2);
        part += __shfl_xor(part, 4);
        part += __shfl_xor(part, 8);
        part += __shfl_xor(part, 16);
        if (lane32 == 0 && l < LWIN) out[b * LWIN + l] = fmaf(0.2f, part, cs[496]);
    }
}

extern "C" void kernel_launch(void* const* d_in, const int* in_sizes, int n_in,
                              void* d_out, int out_size, void* d_ws, size_t ws_size,
                              hipStream_t stream) {
    const float* eeg  = (const float*)d_in[0];
    // d_in[1] = env, unused by the reference computation
    const float* c1w  = (const float*)d_in[2];
    const float* c1b  = (const float*)d_in[3];
    const float* bn1g = (const float*)d_in[4];
    const float* bn1b = (const float*)d_in[5];
    const float* bn1m = (const float*)d_in[6];
    const float* bn1v = (const float*)d_in[7];
    const float* w2   = (const float*)d_in[8];
    const float* c2b  = (const float*)d_in[9];
    const float* bn2g = (const float*)d_in[10];
    const float* bn2b = (const float*)d_in[11];
    const float* bn2m = (const float*)d_in[12];
    const float* bn2v = (const float*)d_in[13];
    const float* c3w  = (const float*)d_in[14];
    const float* c3b  = (const float*)d_in[15];
    const float* c4w  = (const float*)d_in[16];
    const float* c4b  = (const float*)d_in[17];
    const float* bn3g = (const float*)d_in[18];
    const float* bn3b = (const float*)d_in[19];
    const float* bn3m = (const float*)d_in[20];
    const float* bn3v = (const float*)d_in[21];
    const float* linw = (const float*)d_in[22];
    const float* linb = (const float*)d_in[23];

    eegnet_fused<<<dim3(16, NBL), 512, 0, stream>>>(
        eeg, c1w, c1b, bn1g, bn1b, bn1m, bn1v, w2, c2b,
        bn2g, bn2b, bn2m, bn2v, c3w, c3b, c4w, c4b,
        bn3g, bn3b, bn3m, bn3v, linw, linb, (float*)d_out);
}

// Round 8
// 19.145 us; speedup vs baseline: 1.0369x; 1.0369x over previous
//
#include <hip/hip_runtime.h>
#include <math.h>

#define BN_EPS 1e-5f
#define LWIN   193     // 256 - 64 + 1 windows
#define WPB    16      // windows per block
#define NBL    13      // ceil(193/16)
#define SLOC   96      // local sequence positions per block (79 real + halo)
#define STR    97      // LDS row stride for phase arrays

typedef __attribute__((address_space(1))) const unsigned int gl_u32;
typedef __attribute__((address_space(3))) unsigned int lds_u32;

__device__ __forceinline__ float elu(float x) { return x > 0.f ? x : expm1f(x); }

// r5 structure (best: 15.5us), minus 4 barriers:
//  - staging: EACH wave DMAs the full Eg slice (identical values -> benign
//    LDS race) and writes its OWN w2t4 slice; per-wave s_waitcnt replaces the
//    staging barrier, and the cs fold overlaps the U phase.
//  - P2 inlined into Q; Y1 moved into the Q phase slot; S5 inlined into Y2.
// All phase math bit-identical to r5 (validated absmax 0.0).
// Phases: stage | U | E | Q+Y1 | Ef | Y2   (4 barriers).
__global__ __launch_bounds__(256) void eegnet_fused(
    const float* __restrict__ eeg,
    const float* __restrict__ c1w, const float* __restrict__ c1b,
    const float* __restrict__ bn1g, const float* __restrict__ bn1b,
    const float* __restrict__ bn1m, const float* __restrict__ bn1v,
    const float* __restrict__ w2,  const float* __restrict__ c2b,
    const float* __restrict__ bn2g, const float* __restrict__ bn2b,
    const float* __restrict__ bn2m, const float* __restrict__ bn2v,
    const float* __restrict__ c3w, const float* __restrict__ c3b,
    const float* __restrict__ c4w, const float* __restrict__ c4b,
    const float* __restrict__ bn3g, const float* __restrict__ bn3b,
    const float* __restrict__ bn3m, const float* __restrict__ bn3v,
    const float* __restrict__ linw, const float* __restrict__ linb,
    float* __restrict__ out)
{
    const int b   = blockIdx.x;
    const int L0  = blockIdx.y * WPB;
    const int g0  = L0 - 3;
    const int tid = threadIdx.x;
    const int lane16 = tid & 15;
    const int grp16  = tid >> 4;

    __shared__ __align__(16) float Eg[64 * SLOC];  // eeg slice, stride 96
    __shared__ float4 w2t4[64 * 4];      // [c][og]: w2 transposed, 4 o per float4
    __shared__ float  Ul[16][STR], El[16][STR], Ql[16][STR], Ef[16][STR];
    __shared__ float  cs[512];           // folded constants (layout as r5)
    __shared__ __align__(16) float q0s[16][20], q1s[16][20];

    const float* ebase = eeg + b * 64 * 256;

    // ---- stage eeg -> LDS: EVERY wave issues all 24 chunks (same data,
    //      benign race) so only a per-wave waitcnt is needed before U.
    //      Edge chunks: per-element clamped fallback (r4 lesson). ----
    {
        const int ln = tid & 63;
        #pragma unroll
        for (int n = 0; n < 24; ++n) {
            const int fidx = n * 256 + ln * 4;    // dest float index
            const int c    = fidx / SLOC;         // SLOC%4==0 -> chunk in-row
            const int i    = fidx - c * SLOC;
            const int s    = g0 + i;
            if (s >= 0 && s <= 252) {
                __builtin_amdgcn_global_load_lds((gl_u32*)(ebase + c * 256 + s),
                                                 (lds_u32*)&Eg[n * 256], 16, 0, 0);
            } else {
                const float* row = ebase + c * 256;
                const int e0 = s     < 0 ? 0 : (s     > 255 ? 255 : s);
                const int e1 = s + 1 < 0 ? 0 : (s + 1 > 255 ? 255 : s + 1);
                const int e2 = s + 2 < 0 ? 0 : (s + 2 > 255 ? 255 : s + 2);
                const int e3 = s + 3 < 0 ? 0 : (s + 3 > 255 ? 255 : s + 3);
                *reinterpret_cast<float4*>(&Eg[fidx]) =
                    make_float4(row[e0], row[e1], row[e2], row[e3]);
            }
        }
    }

    // ---- w2 -> LDS transposed: wave og writes exactly its own slice ----
    {
        const int og = tid >> 6, c = tid & 63, o0 = og * 4;
        w2t4[c * 4 + og] = make_float4(w2[(o0    ) * 64 + c], w2[(o0 + 1) * 64 + c],
                                       w2[(o0 + 2) * 64 + c], w2[(o0 + 3) * 64 + c]);
    }

    // per-wave drain: my DMA chunks + my w2t4 writes are visible to my lanes
    asm volatile("s_waitcnt vmcnt(0) lgkmcnt(0)" ::: "memory");
    __builtin_amdgcn_sched_barrier(0);

    // ---- U phase: wave og owns channels 4og..4og+3 (no block barrier yet) ----
    {
        const int p  = tid & 63;
        const int og = tid >> 6;
        const bool two = (p < 32);
        float a0 = 0.f, a1 = 0.f, a2 = 0.f, a3 = 0.f;
        float b0 = 0.f, b1 = 0.f, b2 = 0.f, b3 = 0.f;
        #pragma unroll 8
        for (int c = 0; c < 64; ++c) {
            const float4 w = w2t4[c * 4 + og];       // ds_read_b128, wave-uniform
            const float  e = Eg[c * SLOC + p];       // conflict-free (2-way max)
            a0 = fmaf(w.x, e, a0); a1 = fmaf(w.y, e, a1);
            a2 = fmaf(w.z, e, a2); a3 = fmaf(w.w, e, a3);
            if (two) {
                const float e2 = Eg[c * SLOC + p + 64];
                b0 = fmaf(w.x, e2, b0); b1 = fmaf(w.y, e2, b1);
                b2 = fmaf(w.z, e2, b2); b3 = fmaf(w.w, e2, b3);
            }
        }
        const int o0 = og * 4;
        Ul[o0    ][p] = a0; Ul[o0 + 1][p] = a1;
        Ul[o0 + 2][p] = a2; Ul[o0 + 3][p] = a3;
        if (two) {
            Ul[o0    ][p + 64] = b0; Ul[o0 + 1][p + 64] = b1;
            Ul[o0 + 2][p + 64] = b2; Ul[o0 + 3][p + 64] = b3;
        }
    }

    // ---- fold constants (overlaps U on waves 0-3; consumed after barrier) ----
    if (tid < 64) {
        const int f = tid & 15, q = tid >> 4;
        float s2p = 0.f;
        #pragma unroll
        for (int k = 0; k < 16; ++k) s2p += w2[f * 64 + q * 16 + k];
        s2p += __shfl_xor(s2p, 16);
        s2p += __shfl_xor(s2p, 32);
        if (tid < 16) {
            const int g = f >> 1;
            const float s1 = bn1g[g] / sqrtf(bn1v[g] + BN_EPS);
            const float o1 = bn1b[g] - bn1m[g] * s1;
            const float s2 = bn2g[f] / sqrtf(bn2v[f] + BN_EPS);
            const float o2 = bn2b[f] - bn2m[f] * s2;
            const float ss = s2 * s1;
            cs[      f] = ss * c1w[g * 3 + 0];
            cs[ 16 + f] = ss * c1w[g * 3 + 1];
            cs[ 32 + f] = ss * c1w[g * 3 + 2];
            cs[ 48 + f] = s2 * (fmaf(s1, c1b[g], o1) * s2p + c2b[f]) + o2;
            cs[ 64 + f] = c3w[f * 3 + 0];
            cs[ 80 + f] = c3w[f * 3 + 1];
            cs[ 96 + f] = c3w[f * 3 + 2];
            cs[112 + f] = c3b[f];
        }
    } else if (tid < 128) {
        const int j = tid - 64, f = j & 15, quad = j >> 4;
        const float s3 = bn3g[f] / sqrtf(bn3v[f] + BN_EPS);
        if (quad == 0)
            cs[128 + f] = fmaf(s3, c4b[f], bn3b[f] - bn3m[f] * s3);
        #pragma unroll
        for (int k = 0; k < 4; ++k) {
            const int o = quad * 4 + k;
            cs[144 + o * 16 + f] = s3 * c4w[f * 16 + o];
        }
    } else if (tid < 224) {
        cs[400 + tid - 128] = linw[tid - 128];
    } else if (tid == 224) {
        cs[496] = linb[0];
    }
    __syncthreads();   // Ul + cs ready

    // ---- E phase (global zero-pad at s=0 / s=255) ----
    #pragma unroll
    for (int k = 0; k < 6; ++k) {
        const int i = grp16 + 16 * k, sg = g0 + i, o = lane16;
        const float um = (sg >= 1)   ? Ul[o][i > 0 ? i - 1 : 0] : 0.f;
        const float uc = Ul[o][i];
        const float up = (sg <= 254) ? Ul[o][i < SLOC - 1 ? i + 1 : SLOC - 1] : 0.f;
        El[o][i] = elu(fmaf(cs[o], um, fmaf(cs[16 + o], uc, fmaf(cs[32 + o], up, cs[48 + o]))));
    }
    __syncthreads();

    // ---- Q phase (P2 inline, bit-identical clamps) + Y1 fused ----
    {
        const int o = lane16;
        #pragma unroll
        for (int k = 0; k < 6; ++k) {
            const int i  = grp16 + 16 * k;
            const int im = i >= 2 ? i - 2 : 0;
            const int ip = i < SLOC - 2 ? i + 2 : SLOC - 1;
            const float pm = 0.5f * (El[o][im] + El[o][im < SLOC - 1 ? im + 1 : SLOC - 1]);
            const float pc = 0.5f * (El[o][i ] + El[o][i  < SLOC - 1 ? i  + 1 : SLOC - 1]);
            const float pp = 0.5f * (El[o][ip] + El[o][ip < SLOC - 1 ? ip + 1 : SLOC - 1]);
            Ql[o][i] = fmaf(cs[64 + o], pm,
                       fmaf(cs[80 + o], pc,
                       fmaf(cs[96 + o], pp, cs[112 + o])));
        }
        // Y1: thread (w = grp16, o = lane16)
        const int w = grp16, l = L0 + w;
        if (l < LWIN) {
            const int li = w + 3;
            const float z0 = fmaf(cs[16 + o], Ul[o][li],
                             fmaf(cs[32 + o], Ul[o][li + 1], cs[48 + o]));
            const float P0 = 0.5f * (elu(z0) + El[o][li + 1]);
            const float pa = 0.5f * (El[o][li + 2] + El[o][li + 3]);
            const float pb = 0.5f * (El[o][li + 4] + El[o][li + 5]);
            q0s[w][o] = fmaf(cs[80 + o], P0, fmaf(cs[96 + o], pa, cs[112 + o]));
            q1s[w][o] = fmaf(cs[64 + o], P0,
                        fmaf(cs[80 + o], pa, fmaf(cs[96 + o], pb, cs[112 + o])));
        }
    }
    __syncthreads();

    // ---- Ef phase: 1x1 conv + bn3 + elu ----
    #pragma unroll
    for (int k = 0; k < 6; ++k) {
        const int i = grp16 + 16 * k, f = lane16;
        float r = cs[128 + f];
        #pragma unroll
        for (int o = 0; o < 16; ++o)
            r = fmaf(cs[144 + o * 16 + f], Ql[o][i], r);
        Ef[f][i] = elu(r);
    }
    __syncthreads();

    // ---- Y2: per-window output with S5 inlined; reduce over f ----
    {
        const int w = grp16, f = lane16, l = L0 + w;
        float part = 0.f;
        if (l < LWIN) {
            const int li = w + 3;
            float r0 = cs[128 + f], r1 = r0;
            const float4* q04 = reinterpret_cast<const float4*>(&q0s[w][0]);
            const float4* q14 = reinterpret_cast<const float4*>(&q1s[w][0]);
            #pragma unroll
            for (int ov = 0; ov < 4; ++ov) {
                const float4 a = q04[ov], c = q14[ov];
                r0 = fmaf(cs[144 + (4*ov    ) * 16 + f], a.x, r0);
                r0 = fmaf(cs[144 + (4*ov + 1) * 16 + f], a.y, r0);
                r0 = fmaf(cs[144 + (4*ov + 2) * 16 + f], a.z, r0);
                r0 = fmaf(cs[144 + (4*ov + 3) * 16 + f], a.w, r0);
                r1 = fmaf(cs[144 + (4*ov    ) * 16 + f], c.x, r1);
                r1 = fmaf(cs[144 + (4*ov + 1) * 16 + f], c.y, r1);
                r1 = fmaf(cs[144 + (4*ov + 2) * 16 + f], c.z, r1);
                r1 = fmaf(cs[144 + (4*ov + 3) * 16 + f], c.w, r1);
            }
            part = cs[400 + f * 6] * (elu(r0) + elu(r1) - Ef[f][li] - Ef[f][li + 2]);
            #pragma unroll
            for (int g = 0; g < 6; ++g) {
                const int p0 = li + 10 * g;
                const float s5 = Ef[f][p0] + Ef[f][p0 + 2] + Ef[f][p0 + 4]
                               + Ef[f][p0 + 6] + Ef[f][p0 + 8];
                part = fmaf(cs[400 + f * 6 + g], s5, part);
            }
        }
        part += __shfl_xor(part, 1);
        part += __shfl_xor(part, 2);
        part += __shfl_xor(part, 4);
        part += __shfl_xor(part, 8);
        if (f == 0 && l < LWIN) out[b * LWIN + l] = fmaf(0.2f, part, cs[496]);
    }
}

extern "C" void kernel_launch(void* const* d_in, const int* in_sizes, int n_in,
                              void* d_out, int out_size, void* d_ws, size_t ws_size,
                              hipStream_t stream) {
    const float* eeg  = (const float*)d_in[0];
    // d_in[1] = env, unused by the reference computation
    const float* c1w  = (const float*)d_in[2];
    const float* c1b  = (const float*)d_in[3];
    const float* bn1g = (const float*)d_in[4];
    const float* bn1b = (const float*)d_in[5];
    const float* bn1m = (const float*)d_in[6];
    const float* bn1v = (const float*)d_in[7];
    const float* w2   = (const float*)d_in[8];
    const float* c2b  = (const float*)d_in[9];
    const float* bn2g = (const float*)d_in[10];
    const float* bn2b = (const float*)d_in[11];
    const float* bn2m = (const float*)d_in[12];
    const float* bn2v = (const float*)d_in[13];
    const float* c3w  = (const float*)d_in[14];
    const float* c3b  = (const float*)d_in[15];
    const float* c4w  = (const float*)d_in[16];
    const float* c4b  = (const float*)d_in[17];
    const float* bn3g = (const float*)d_in[18];
    const float* bn3b = (const float*)d_in[19];
    const float* bn3m = (const float*)d_in[20];
    const float* bn3v = (const float*)d_in[21];
    const float* linw = (const float*)d_in[22];
    const float* linb = (const float*)d_in[23];

    eegnet_fused<<<dim3(16, NBL), 256, 0, stream>>>(
        eeg, c1w, c1b, bn1g, bn1b, bn1m, bn1v, w2, c2b,
        bn2g, bn2b, bn2m, bn2v, c3w, c3b, c4w, c4b,
        bn3g, bn3b, bn3m, bn3v, linw, linb, (float*)d_out);
}